// Round 19
// baseline (78.965 us; speedup 1.0000x reference)
//
#include <hip/hip_runtime.h>
#include <stdint.h>

// Problem constants
#define M_ROWS   16000        // B*T
#define D_IN     320
#define E_DIM    16
#define K_CB     8192
#define NCHUNK   32           // k-chunks: 16 k-tiles (256 codewords) each
#define KT_PER_CHUNK 16
#define RPT      4            // row-tiles per wave (flat; 3 LDS reads serve 12 MFMAs)
#define NRB      64           // row-blocks (16 rt each; rb=63 is dummy padding)

typedef __attribute__((ext_vector_type(8))) short bf16x8;
typedef __attribute__((ext_vector_type(4))) float f32x4;

// Workspace layout (bytes) — XA/XB padded to 1024 tiles for the dummy rb
#define XA_OFF   0u                       // [1024 tiles][64 lanes][8 bf16]  (h|m)
#define XB_OFF   1048576u                 // same shape                       (l|h)
#define CBA_OFF  2097152u                 // [512 ktiles][64 lanes][8 bf16]  (h'|m')
#define CBC_OFF  2621440u                 // same                             (h'|l')
#define KEYS_OFF 3145728u                 // [16384] u64 per-row keys

#define AS1 __attribute__((address_space(1)))
#define AS3 __attribute__((address_space(3)))

__device__ __forceinline__ unsigned short f2bf(float x) {
    union { float f; unsigned u; } v; v.f = x;
    unsigned r = v.u + 0x7FFFu + ((v.u >> 16) & 1u);   // round-to-nearest-even
    return (unsigned short)(r >> 16);
}
__device__ __forceinline__ float bf2f(unsigned short b) {
    union { unsigned u; float f; } v; v.u = ((unsigned)b) << 16; return v.f;
}

// ---------- Fused prep ----------
// Projection (blocks 0..999): split-K x4 — thread = (row, eq, ks); each of 4
// k-slice lanes sums 80 dims (20 iters), shfl_xor tree combine, ks==0 lane
// split-packs (identical pack math/addressing to r18). 256000 threads ->
// ~4 waves/SIMD (was 1) to hide the load latency that made prep ~14 us.
// Codebook split-pack + keys init (blocks 1000..1127): byte-identical to r18.
__global__ __launch_bounds__(256) void prep_kernel(const float* __restrict__ hs,
                                                   const float* __restrict__ P,
                                                   const float* __restrict__ CB,
                                                   unsigned short* __restrict__ Xa,
                                                   unsigned short* __restrict__ Xb,
                                                   unsigned short* __restrict__ CBa,
                                                   unsigned short* __restrict__ CBc,
                                                   unsigned long long* __restrict__ keys) {
    int bid = blockIdx.x;
    int t   = threadIdx.x;
    if (bid < 1000) {
        int row = bid * 16 + (t >> 4);            // 16 rows/block, exact 16000
        int eq  = (t >> 2) & 3;
        int ks  = t & 3;                          // k-slice: dims [ks*80, ks*80+80)
        const float* hrow = hs + (size_t)row * D_IN + ks * 80;
        const float* pbase = P + (size_t)ks * 80 * E_DIM + eq * 4;
        float ax = 0.f, ay = 0.f, az = 0.f, aw = 0.f;
        #pragma unroll 4
        for (int d = 0; d < 80; d += 4) {
            float4 h4 = *reinterpret_cast<const float4*>(hrow + d);
            float4 p0 = *reinterpret_cast<const float4*>(pbase + (size_t)(d + 0) * E_DIM);
            float4 p1 = *reinterpret_cast<const float4*>(pbase + (size_t)(d + 1) * E_DIM);
            float4 p2 = *reinterpret_cast<const float4*>(pbase + (size_t)(d + 2) * E_DIM);
            float4 p3 = *reinterpret_cast<const float4*>(pbase + (size_t)(d + 3) * E_DIM);
            ax += h4.x * p0.x + h4.y * p1.x + h4.z * p2.x + h4.w * p3.x;
            ay += h4.x * p0.y + h4.y * p1.y + h4.z * p2.y + h4.w * p3.y;
            az += h4.x * p0.z + h4.y * p1.z + h4.z * p2.z + h4.w * p3.z;
            aw += h4.x * p0.w + h4.y * p1.w + h4.z * p2.w + h4.w * p3.w;
        }
        // tree-combine the 4 k-slices (adjacent lanes, xor 1 then xor 2)
        ax += __shfl_xor(ax, 1, 64);  ay += __shfl_xor(ay, 1, 64);
        az += __shfl_xor(az, 1, 64);  aw += __shfl_xor(aw, 1, 64);
        ax += __shfl_xor(ax, 2, 64);  ay += __shfl_xor(ay, 2, 64);
        az += __shfl_xor(az, 2, 64);  aw += __shfl_xor(aw, 2, 64);
        if (ks == 0) {
            float v[4] = {ax, ay, az, aw};
            ushort4 h, m, l;
            unsigned short* hp = (unsigned short*)&h;
            unsigned short* mp = (unsigned short*)&m;
            unsigned short* lp = (unsigned short*)&l;
            #pragma unroll
            for (int i = 0; i < 4; ++i) {
                unsigned short hb = f2bf(v[i]);      float r1 = v[i] - bf2f(hb);
                unsigned short mb = f2bf(r1);        float r2 = r1 - bf2f(mb);
                unsigned short lb = f2bf(r2);        // exact: v = h + m + l
                hp[i] = hb; mp[i] = mb; lp[i] = lb;
            }
            int rt = row >> 4, rl = row & 15;
            int g  = eq >> 1;
            int j0 = (eq & 1) * 4;
            size_t base = (size_t)rt * 512;
            *reinterpret_cast<ushort4*>(Xa + base + ((g    ) * 16 + rl) * 8 + j0) = h;
            *reinterpret_cast<ushort4*>(Xa + base + ((2 + g) * 16 + rl) * 8 + j0) = m;
            *reinterpret_cast<ushort4*>(Xb + base + ((g    ) * 16 + rl) * 8 + j0) = l;
            *reinterpret_cast<ushort4*>(Xb + base + ((2 + g) * 16 + rl) * 8 + j0) = h;
        }
    } else {
        int bid2 = bid - 1000;                    // 0..127
        int gid  = bid2 * 256 + t;
        if (gid < 16384) keys[gid] = 0ull;        // fused keys init (scores map to mono>0)
        int c  = bid2 * 64 + (t >> 2);
        int eq = t & 3;
        float4 v4 = *reinterpret_cast<const float4*>(CB + (size_t)c * E_DIM + eq * 4);
        float v[4] = {v4.x, v4.y, v4.z, v4.w};
        ushort4 h, m, l;
        unsigned short* hp = (unsigned short*)&h;
        unsigned short* mp = (unsigned short*)&m;
        unsigned short* lp = (unsigned short*)&l;
        #pragma unroll
        for (int i = 0; i < 4; ++i) {
            unsigned short hb = f2bf(v[i]);      float r1 = v[i] - bf2f(hb);
            unsigned short mb = f2bf(r1);        float r2 = r1 - bf2f(mb);
            unsigned short lb = f2bf(r2);
            hp[i] = hb; mp[i] = mb; lp[i] = lb;
        }
        int kt = c >> 4, cl = c & 15;
        int g  = eq >> 1;
        int j0 = (eq & 1) * 4;
        size_t base = (size_t)kt * 512;
        *reinterpret_cast<ushort4*>(CBa + base + ((g    ) * 16 + cl) * 8 + j0) = h;
        *reinterpret_cast<ushort4*>(CBa + base + ((2 + g) * 16 + cl) * 8 + j0) = m;
        *reinterpret_cast<ushort4*>(CBc + base + ((g    ) * 16 + cl) * 8 + j0) = h;
        *reinterpret_cast<ushort4*>(CBc + base + ((2 + g) * 16 + cl) * 8 + j0) = l;
    }
}

// ---------- MFMA score + fused argmax (byte-identical to verified r18) ----------
__global__ __launch_bounds__(256, 5) void score_kernel(const unsigned short* __restrict__ Xa,
                                                       const unsigned short* __restrict__ Xb,
                                                       const unsigned short* __restrict__ CBa,
                                                       const unsigned short* __restrict__ CBc,
                                                       unsigned long long* __restrict__ keys) {
    __shared__ unsigned short sA[KT_PER_CHUNK * 512];   // 16 KB  (h'|m')
    __shared__ unsigned short sC[KT_PER_CHUNK * 512];   // 16 KB  (h'|l')

    int t    = threadIdx.x;
    int lane = t & 63;
    int w    = t >> 6;                // 0..3
    int bid  = blockIdx.x;            // 0..2047
    int xcd  = bid & 7;
    int idx  = bid >> 3;              // 0..255
    int j    = idx & 7;
    int kc   = idx >> 3;              // 0..31
    int rb   = xcd + 8 * j;           // 0..63 (rb=63 dummy), clustered per XCD
    int rt0  = rb * 16 + w * RPT;

    // Stage both B streams for the whole k-chunk (4 glds rounds each) FIRST.
    {
        const unsigned char* ga = (const unsigned char*)(CBa + (size_t)kc * KT_PER_CHUNK * 512);
        const unsigned char* gc = (const unsigned char*)(CBc + (size_t)kc * KT_PER_CHUNK * 512);
        unsigned char* la = (unsigned char*)sA;
        unsigned char* lc = (unsigned char*)sC;
        int wo = w * 1024 + lane * 16;
        #pragma unroll
        for (int q = 0; q < 4; ++q)
            __builtin_amdgcn_global_load_lds((const AS1 void*)(ga + q * 4096 + wo),
                                             (AS3 void*)(la + q * 4096 + w * 1024), 16, 0, 0);
        #pragma unroll
        for (int q = 0; q < 4; ++q)
            __builtin_amdgcn_global_load_lds((const AS1 void*)(gc + q * 4096 + wo),
                                             (AS3 void*)(lc + q * 4096 + w * 1024), 16, 0, 0);
    }

    // Issue ALL A-fragment loads now — latency overlaps the staging drain.
    bf16x8 a_hm[RPT], a_lh[RPT];
    #pragma unroll
    for (int r = 0; r < RPT; ++r) {
        a_hm[r] = *reinterpret_cast<const bf16x8*>(Xa + ((size_t)(rt0 + r) * 64 + lane) * 8);
        a_lh[r] = *reinterpret_cast<const bf16x8*>(Xb + ((size_t)(rt0 + r) * 64 + lane) * 8);
    }

    float best[RPT][4];
    int   bidx[RPT][4];
    #pragma unroll
    for (int r = 0; r < RPT; ++r)
        #pragma unroll
        for (int i = 0; i < 4; ++i) { best[r][i] = -3.0e38f; bidx[r][i] = 0; }

    __syncthreads();   // compiler emits vmcnt(0) drain: staging + A-loads done

    const bf16x8* sA8 = reinterpret_cast<const bf16x8*>(sA);
    const bf16x8* sC8 = reinterpret_cast<const bf16x8*>(sC);
    int lsw  = lane ^ 32;             // swapped-half lane for the [m'|h'] operand
    int colc = lane & 15;

    #pragma unroll 2
    for (int kt = 0; kt < KT_PER_CHUNK; ++kt) {
        bf16x8 c1 = sA8[kt * 64 + lane];
        bf16x8 c2 = sA8[kt * 64 + lsw];
        bf16x8 c3 = sC8[kt * 64 + lane];
        #pragma unroll
        for (int r = 0; r < RPT; ++r) {
            f32x4 acc = {0.f, 0.f, 0.f, 0.f};
            acc = __builtin_amdgcn_mfma_f32_16x16x32_bf16(a_hm[r], c1, acc, 0, 0, 0); // hh+mm
            acc = __builtin_amdgcn_mfma_f32_16x16x32_bf16(a_hm[r], c2, acc, 0, 0, 0); // hm+mh
            acc = __builtin_amdgcn_mfma_f32_16x16x32_bf16(a_lh[r], c3, acc, 0, 0, 0); // lh+hl
            #pragma unroll
            for (int i = 0; i < 4; ++i) {
                bool gt = acc[i] > best[r][i];
                best[r][i] = gt ? acc[i] : best[r][i];
                bidx[r][i] = gt ? kt     : bidx[r][i];
            }
        }
    }

    // u64-key shfl reduce over the 16 columns; one atomicMax per row.
    // Key = mono(score)<<32 | ~idx (verified round-2 semantics).
    #pragma unroll
    for (int r = 0; r < RPT; ++r) {
        #pragma unroll
        for (int i = 0; i < 4; ++i) {
            unsigned u    = __float_as_uint(best[r][i]);
            unsigned mono = (u & 0x80000000u) ? ~u : (u | 0x80000000u);
            unsigned kg   = (unsigned)(kc * 256 + bidx[r][i] * 16 + colc);
            unsigned long long key = ((unsigned long long)mono << 32) | (unsigned)(~kg);
            #pragma unroll
            for (int off = 1; off <= 8; off <<= 1) {
                unsigned long long ok =
                    (((unsigned long long)(unsigned)__shfl_xor((int)(key >> 32), off, 64)) << 32) |
                    (unsigned)__shfl_xor((int)(unsigned)key, off, 64);
                key = (ok > key) ? ok : key;
            }
            if (colc == 0) {
                int row = (rt0 + r) * 16 + (lane >> 4) * 4 + i;
                if (row < M_ROWS) atomicMax(keys + row, key);
            }
        }
    }
}

// ---------- Decode: keys -> int32 indices (elementwise) ----------
__global__ __launch_bounds__(256) void decode_kernel(const unsigned long long* __restrict__ keys,
                                                     int* __restrict__ out) {
    int i = blockIdx.x * 256 + threadIdx.x;
    if (i < M_ROWS) out[i] = (int)(~(unsigned)(keys[i] & 0xFFFFFFFFull));
}

extern "C" void kernel_launch(void* const* d_in, const int* in_sizes, int n_in,
                              void* d_out, int out_size, void* d_ws, size_t ws_size,
                              hipStream_t stream) {
    const float* hs = (const float*)d_in[0];   // [8,2000,320]
    const float* P  = (const float*)d_in[1];   // [1,320,16]
    const float* CB = (const float*)d_in[2];   // [1,8192,16]
    int* out = (int*)d_out;                    // [8,1,2000] int32

    char* ws = (char*)d_ws;
    unsigned short* Xa  = (unsigned short*)(ws + XA_OFF);
    unsigned short* Xb  = (unsigned short*)(ws + XB_OFF);
    unsigned short* CBa = (unsigned short*)(ws + CBA_OFF);
    unsigned short* CBc = (unsigned short*)(ws + CBC_OFF);
    unsigned long long* keys = (unsigned long long*)(ws + KEYS_OFF);

    prep_kernel<<<dim3(1128), dim3(256), 0, stream>>>(hs, P, CB, Xa, Xb, CBa, CBc, keys);
    score_kernel<<<dim3(NRB * NCHUNK), dim3(256), 0, stream>>>(Xa, Xb, CBa, CBc, keys);
    decode_kernel<<<dim3(63), dim3(256), 0, stream>>>(keys, out);
}

// Round 20
// 46.559 us; speedup vs baseline: 1.6960x; 1.6960x over previous
//
#include <hip/hip_runtime.h>
#include <stdint.h>

// Problem constants
#define M_ROWS   16000        // B*T
#define D_IN     320
#define E_DIM    16
#define K_CB     8192
#define NCHUNK   32           // k-chunks: 16 k-tiles (256 codewords) each
#define KT_PER_CHUNK 16
#define RPT      4            // row-tiles per wave (flat; 3 LDS reads serve 12 MFMAs)
#define NRB      64           // row-blocks (16 rt each; rb=63 is dummy padding)

typedef __attribute__((ext_vector_type(8))) short bf16x8;
typedef __attribute__((ext_vector_type(4))) float f32x4;

// Workspace layout (bytes) — XA/XB padded to 1024 tiles for the dummy rb
#define XA_OFF   0u                       // [1024 tiles][64 lanes][8 bf16]  (h|m)
#define XB_OFF   1048576u                 // same shape                       (l|h)
#define CBA_OFF  2097152u                 // [512 ktiles][64 lanes][8 bf16]  (h'|m')
#define CBC_OFF  2621440u                 // same                             (h'|l')
#define KEYS_OFF 3145728u                 // [16384] u64 per-row keys

#define AS1 __attribute__((address_space(1)))
#define AS3 __attribute__((address_space(3)))

__device__ __forceinline__ unsigned short f2bf(float x) {
    union { float f; unsigned u; } v; v.f = x;
    unsigned r = v.u + 0x7FFFu + ((v.u >> 16) & 1u);   // round-to-nearest-even
    return (unsigned short)(r >> 16);
}
__device__ __forceinline__ float bf2f(unsigned short b) {
    union { unsigned u; float f; } v; v.u = ((unsigned)b) << 16; return v.f;
}

// ---------- Fused prep ----------
// Projection (blocks 0..999): split-K x4 (r19's wave count: ~4 waves/SIMD) but
// with P staged in LDS — r19's regression was the P-load scatter (16 distinct
// 16B global transactions/instr); from LDS the scatter is free. Per-ks slab
// padded to stride 322 float4 so the 16 (eq,ks) addresses land 2-per-bank.
// Inner loop: 1 global float4 (hs) + 4 LDS float4 + 16 FMA.
// Codebook split-pack + keys init (blocks 1000..1127): byte-identical to r18.
__global__ __launch_bounds__(256) void prep_kernel(const float* __restrict__ hs,
                                                   const float* __restrict__ P,
                                                   const float* __restrict__ CB,
                                                   unsigned short* __restrict__ Xa,
                                                   unsigned short* __restrict__ Xb,
                                                   unsigned short* __restrict__ CBa,
                                                   unsigned short* __restrict__ CBc,
                                                   unsigned long long* __restrict__ keys) {
    __shared__ float4 sP4[4 * 322];               // 4 ks-slabs x (320+2) float4 = 20.6 KB
    int bid = blockIdx.x;
    int t   = threadIdx.x;
    if (bid < 1000) {
        // Stage P into LDS: 1280 float4, coalesced; dest = f + 2*(f/320) (slab pad)
        const float4* P4 = reinterpret_cast<const float4*>(P);
        #pragma unroll
        for (int q = 0; q < 5; ++q) {
            int f = t + 256 * q;
            sP4[f + 2 * (f / 320)] = P4[f];
        }
        __syncthreads();

        int row = bid * 16 + (t >> 4);            // 16 rows/block, exact 16000
        int eq  = (t >> 2) & 3;
        int ks  = t & 3;                          // k-slice: dims [ks*80, ks*80+80)
        const float* hrow = hs + (size_t)row * D_IN + ks * 80;
        const float4* pl  = sP4 + ks * 322 + eq;  // + (d+i)*4 per element
        float ax = 0.f, ay = 0.f, az = 0.f, aw = 0.f;
        #pragma unroll 4
        for (int d = 0; d < 80; d += 4) {
            float4 h4 = *reinterpret_cast<const float4*>(hrow + d);
            float4 p0 = pl[(d + 0) * 4];
            float4 p1 = pl[(d + 1) * 4];
            float4 p2 = pl[(d + 2) * 4];
            float4 p3 = pl[(d + 3) * 4];
            ax += h4.x * p0.x + h4.y * p1.x + h4.z * p2.x + h4.w * p3.x;
            ay += h4.x * p0.y + h4.y * p1.y + h4.z * p2.y + h4.w * p3.y;
            az += h4.x * p0.z + h4.y * p1.z + h4.z * p2.z + h4.w * p3.z;
            aw += h4.x * p0.w + h4.y * p1.w + h4.z * p2.w + h4.w * p3.w;
        }
        // tree-combine the 4 k-slices (adjacent lanes, xor 1 then xor 2)
        ax += __shfl_xor(ax, 1, 64);  ay += __shfl_xor(ay, 1, 64);
        az += __shfl_xor(az, 1, 64);  aw += __shfl_xor(aw, 1, 64);
        ax += __shfl_xor(ax, 2, 64);  ay += __shfl_xor(ay, 2, 64);
        az += __shfl_xor(az, 2, 64);  aw += __shfl_xor(aw, 2, 64);
        if (ks == 0) {
            float v[4] = {ax, ay, az, aw};
            ushort4 h, m, l;
            unsigned short* hp = (unsigned short*)&h;
            unsigned short* mp = (unsigned short*)&m;
            unsigned short* lp = (unsigned short*)&l;
            #pragma unroll
            for (int i = 0; i < 4; ++i) {
                unsigned short hb = f2bf(v[i]);      float r1 = v[i] - bf2f(hb);
                unsigned short mb = f2bf(r1);        float r2 = r1 - bf2f(mb);
                unsigned short lb = f2bf(r2);        // exact: v = h + m + l
                hp[i] = hb; mp[i] = mb; lp[i] = lb;
            }
            int rt = row >> 4, rl = row & 15;
            int g  = eq >> 1;
            int j0 = (eq & 1) * 4;
            size_t base = (size_t)rt * 512;
            *reinterpret_cast<ushort4*>(Xa + base + ((g    ) * 16 + rl) * 8 + j0) = h;
            *reinterpret_cast<ushort4*>(Xa + base + ((2 + g) * 16 + rl) * 8 + j0) = m;
            *reinterpret_cast<ushort4*>(Xb + base + ((g    ) * 16 + rl) * 8 + j0) = l;
            *reinterpret_cast<ushort4*>(Xb + base + ((2 + g) * 16 + rl) * 8 + j0) = h;
        }
    } else {
        int bid2 = bid - 1000;                    // 0..127
        int gid  = bid2 * 256 + t;
        if (gid < 16384) keys[gid] = 0ull;        // fused keys init (scores map to mono>0)
        int c  = bid2 * 64 + (t >> 2);
        int eq = t & 3;
        float4 v4 = *reinterpret_cast<const float4*>(CB + (size_t)c * E_DIM + eq * 4);
        float v[4] = {v4.x, v4.y, v4.z, v4.w};
        ushort4 h, m, l;
        unsigned short* hp = (unsigned short*)&h;
        unsigned short* mp = (unsigned short*)&m;
        unsigned short* lp = (unsigned short*)&l;
        #pragma unroll
        for (int i = 0; i < 4; ++i) {
            unsigned short hb = f2bf(v[i]);      float r1 = v[i] - bf2f(hb);
            unsigned short mb = f2bf(r1);        float r2 = r1 - bf2f(mb);
            unsigned short lb = f2bf(r2);
            hp[i] = hb; mp[i] = mb; lp[i] = lb;
        }
        int kt = c >> 4, cl = c & 15;
        int g  = eq >> 1;
        int j0 = (eq & 1) * 4;
        size_t base = (size_t)kt * 512;
        *reinterpret_cast<ushort4*>(CBa + base + ((g    ) * 16 + cl) * 8 + j0) = h;
        *reinterpret_cast<ushort4*>(CBa + base + ((2 + g) * 16 + cl) * 8 + j0) = m;
        *reinterpret_cast<ushort4*>(CBc + base + ((g    ) * 16 + cl) * 8 + j0) = h;
        *reinterpret_cast<ushort4*>(CBc + base + ((2 + g) * 16 + cl) * 8 + j0) = l;
    }
}

// ---------- MFMA score + fused argmax (byte-identical to verified r18) ----------
__global__ __launch_bounds__(256, 5) void score_kernel(const unsigned short* __restrict__ Xa,
                                                       const unsigned short* __restrict__ Xb,
                                                       const unsigned short* __restrict__ CBa,
                                                       const unsigned short* __restrict__ CBc,
                                                       unsigned long long* __restrict__ keys) {
    __shared__ unsigned short sA[KT_PER_CHUNK * 512];   // 16 KB  (h'|m')
    __shared__ unsigned short sC[KT_PER_CHUNK * 512];   // 16 KB  (h'|l')

    int t    = threadIdx.x;
    int lane = t & 63;
    int w    = t >> 6;                // 0..3
    int bid  = blockIdx.x;            // 0..2047
    int xcd  = bid & 7;
    int idx  = bid >> 3;              // 0..255
    int j    = idx & 7;
    int kc   = idx >> 3;              // 0..31
    int rb   = xcd + 8 * j;           // 0..63 (rb=63 dummy), clustered per XCD
    int rt0  = rb * 16 + w * RPT;

    // Stage both B streams for the whole k-chunk (4 glds rounds each) FIRST.
    {
        const unsigned char* ga = (const unsigned char*)(CBa + (size_t)kc * KT_PER_CHUNK * 512);
        const unsigned char* gc = (const unsigned char*)(CBc + (size_t)kc * KT_PER_CHUNK * 512);
        unsigned char* la = (unsigned char*)sA;
        unsigned char* lc = (unsigned char*)sC;
        int wo = w * 1024 + lane * 16;
        #pragma unroll
        for (int q = 0; q < 4; ++q)
            __builtin_amdgcn_global_load_lds((const AS1 void*)(ga + q * 4096 + wo),
                                             (AS3 void*)(la + q * 4096 + w * 1024), 16, 0, 0);
        #pragma unroll
        for (int q = 0; q < 4; ++q)
            __builtin_amdgcn_global_load_lds((const AS1 void*)(gc + q * 4096 + wo),
                                             (AS3 void*)(lc + q * 4096 + w * 1024), 16, 0, 0);
    }

    // Issue ALL A-fragment loads now — latency overlaps the staging drain.
    bf16x8 a_hm[RPT], a_lh[RPT];
    #pragma unroll
    for (int r = 0; r < RPT; ++r) {
        a_hm[r] = *reinterpret_cast<const bf16x8*>(Xa + ((size_t)(rt0 + r) * 64 + lane) * 8);
        a_lh[r] = *reinterpret_cast<const bf16x8*>(Xb + ((size_t)(rt0 + r) * 64 + lane) * 8);
    }

    float best[RPT][4];
    int   bidx[RPT][4];
    #pragma unroll
    for (int r = 0; r < RPT; ++r)
        #pragma unroll
        for (int i = 0; i < 4; ++i) { best[r][i] = -3.0e38f; bidx[r][i] = 0; }

    __syncthreads();   // compiler emits vmcnt(0) drain: staging + A-loads done

    const bf16x8* sA8 = reinterpret_cast<const bf16x8*>(sA);
    const bf16x8* sC8 = reinterpret_cast<const bf16x8*>(sC);
    int lsw  = lane ^ 32;             // swapped-half lane for the [m'|h'] operand
    int colc = lane & 15;

    #pragma unroll 2
    for (int kt = 0; kt < KT_PER_CHUNK; ++kt) {
        bf16x8 c1 = sA8[kt * 64 + lane];
        bf16x8 c2 = sA8[kt * 64 + lsw];
        bf16x8 c3 = sC8[kt * 64 + lane];
        #pragma unroll
        for (int r = 0; r < RPT; ++r) {
            f32x4 acc = {0.f, 0.f, 0.f, 0.f};
            acc = __builtin_amdgcn_mfma_f32_16x16x32_bf16(a_hm[r], c1, acc, 0, 0, 0); // hh+mm
            acc = __builtin_amdgcn_mfma_f32_16x16x32_bf16(a_hm[r], c2, acc, 0, 0, 0); // hm+mh
            acc = __builtin_amdgcn_mfma_f32_16x16x32_bf16(a_lh[r], c3, acc, 0, 0, 0); // lh+hl
            #pragma unroll
            for (int i = 0; i < 4; ++i) {
                bool gt = acc[i] > best[r][i];
                best[r][i] = gt ? acc[i] : best[r][i];
                bidx[r][i] = gt ? kt     : bidx[r][i];
            }
        }
    }

    // u64-key shfl reduce over the 16 columns; one atomicMax per row.
    // Key = mono(score)<<32 | ~idx (verified round-2 semantics).
    #pragma unroll
    for (int r = 0; r < RPT; ++r) {
        #pragma unroll
        for (int i = 0; i < 4; ++i) {
            unsigned u    = __float_as_uint(best[r][i]);
            unsigned mono = (u & 0x80000000u) ? ~u : (u | 0x80000000u);
            unsigned kg   = (unsigned)(kc * 256 + bidx[r][i] * 16 + colc);
            unsigned long long key = ((unsigned long long)mono << 32) | (unsigned)(~kg);
            #pragma unroll
            for (int off = 1; off <= 8; off <<= 1) {
                unsigned long long ok =
                    (((unsigned long long)(unsigned)__shfl_xor((int)(key >> 32), off, 64)) << 32) |
                    (unsigned)__shfl_xor((int)(unsigned)key, off, 64);
                key = (ok > key) ? ok : key;
            }
            if (colc == 0) {
                int row = (rt0 + r) * 16 + (lane >> 4) * 4 + i;
                if (row < M_ROWS) atomicMax(keys + row, key);
            }
        }
    }
}

// ---------- Decode: keys -> int32 indices (elementwise) ----------
__global__ __launch_bounds__(256) void decode_kernel(const unsigned long long* __restrict__ keys,
                                                     int* __restrict__ out) {
    int i = blockIdx.x * 256 + threadIdx.x;
    if (i < M_ROWS) out[i] = (int)(~(unsigned)(keys[i] & 0xFFFFFFFFull));
}

extern "C" void kernel_launch(void* const* d_in, const int* in_sizes, int n_in,
                              void* d_out, int out_size, void* d_ws, size_t ws_size,
                              hipStream_t stream) {
    const float* hs = (const float*)d_in[0];   // [8,2000,320]
    const float* P  = (const float*)d_in[1];   // [1,320,16]
    const float* CB = (const float*)d_in[2];   // [1,8192,16]
    int* out = (int*)d_out;                    // [8,1,2000] int32

    char* ws = (char*)d_ws;
    unsigned short* Xa  = (unsigned short*)(ws + XA_OFF);
    unsigned short* Xb  = (unsigned short*)(ws + XB_OFF);
    unsigned short* CBa = (unsigned short*)(ws + CBA_OFF);
    unsigned short* CBc = (unsigned short*)(ws + CBC_OFF);
    unsigned long long* keys = (unsigned long long*)(ws + KEYS_OFF);

    prep_kernel<<<dim3(1128), dim3(256), 0, stream>>>(hs, P, CB, Xa, Xb, CBa, CBc, keys);
    score_kernel<<<dim3(NRB * NCHUNK), dim3(256), 0, stream>>>(Xa, Xb, CBa, CBc, keys);
    decode_kernel<<<dim3(63), dim3(256), 0, stream>>>(keys, out);
}